// Round 4
// baseline (88.269 us; speedup 1.0000x reference)
//
#include <hip/hip_runtime.h>

// Int4 weight-only embedding: out[tok, :] = (weight[x[tok], :] - zp) * scale
// V=128000, D=1024, G_SIZE=32, NG=32. Output fp32.
// R4: 8 tokens per block (8-deep memory-level parallelism per thread),
//     non-temporal f32x4 output stores, normal (cached) weight loads so the
//     ~223 MB gathered working set stays L3-resident across graph replays.

#define EMB_D   1024
#define EMB_NG  32
#define TOKS_PER_BLOCK 8

typedef float f32x4 __attribute__((ext_vector_type(4)));
typedef int   i32x4 __attribute__((ext_vector_type(4)));

__global__ __launch_bounds__(256) void int4_embed_dq_kernel(
    const int*   __restrict__ x,       // [ntok]
    const int*   __restrict__ weight,  // [V, D] int4 values stored as int32
    const float* __restrict__ scale,   // [V, NG]
    const int*   __restrict__ zp,      // [V, NG]
    float*       __restrict__ out,     // [ntok, D]
    int ntok)
{
    const int tok0 = blockIdx.x * TOKS_PER_BLOCK;
    const int t    = threadIdx.x;        // 0..255
    const int d0   = t << 2;             // 0,4,...,1020
    const int g    = d0 >> 5;            // group of 32

    if (tok0 + TOKS_PER_BLOCK <= ntok) {
        int v[TOKS_PER_BLOCK];
#pragma unroll
        for (int i = 0; i < TOKS_PER_BLOCK; ++i)
            v[i] = x[tok0 + i];

        i32x4 w4[TOKS_PER_BLOCK];
        float s [TOKS_PER_BLOCK];
        float z [TOKS_PER_BLOCK];
#pragma unroll
        for (int i = 0; i < TOKS_PER_BLOCK; ++i) {
            const size_t rowW = (size_t)v[i] * EMB_D;
            const size_t rowG = (size_t)v[i] * EMB_NG;
            w4[i] = *reinterpret_cast<const i32x4*>(&weight[rowW + d0]);
            s[i]  = scale[rowG + g];
            z[i]  = (float)zp[rowG + g];
        }
#pragma unroll
        for (int i = 0; i < TOKS_PER_BLOCK; ++i) {
            f32x4 o;
            o.x = ((float)w4[i].x - z[i]) * s[i];
            o.y = ((float)w4[i].y - z[i]) * s[i];
            o.z = ((float)w4[i].z - z[i]) * s[i];
            o.w = ((float)w4[i].w - z[i]) * s[i];
            __builtin_nontemporal_store(
                o, reinterpret_cast<f32x4*>(&out[(size_t)(tok0 + i) * EMB_D + d0]));
        }
    } else {
        for (int i = 0; i < TOKS_PER_BLOCK; ++i) {
            const int tok = tok0 + i;
            if (tok >= ntok) break;
            const int vv = x[tok];
            const size_t rowW = (size_t)vv * EMB_D;
            const size_t rowG = (size_t)vv * EMB_NG;
            const float ss = scale[rowG + g];
            const float zz = (float)zp[rowG + g];
            const i32x4 w4 = *reinterpret_cast<const i32x4*>(&weight[rowW + d0]);
            f32x4 o;
            o.x = ((float)w4.x - zz) * ss;
            o.y = ((float)w4.y - zz) * ss;
            o.z = ((float)w4.z - zz) * ss;
            o.w = ((float)w4.w - zz) * ss;
            __builtin_nontemporal_store(
                o, reinterpret_cast<f32x4*>(&out[(size_t)tok * EMB_D + d0]));
        }
    }
}

extern "C" void kernel_launch(void* const* d_in, const int* in_sizes, int n_in,
                              void* d_out, int out_size, void* d_ws, size_t ws_size,
                              hipStream_t stream) {
    const int*   x      = (const int*)d_in[0];
    const int*   weight = (const int*)d_in[1];
    const float* scale  = (const float*)d_in[2];
    const int*   zp     = (const int*)d_in[3];
    float*       out    = (float*)d_out;

    const int ntok = in_sizes[0];        // 32 * 2048 = 65536

    const int nblocks = (ntok + TOKS_PER_BLOCK - 1) / TOKS_PER_BLOCK;
    int4_embed_dq_kernel<<<dim3(nblocks), dim3(256), 0, stream>>>(
        x, weight, scale, zp, out, ntok);
}

// Round 6
// 87.559 us; speedup vs baseline: 1.0081x; 1.0081x over previous
//
#include <hip/hip_runtime.h>

// Int4 weight-only embedding: out[tok, :] = (weight[x[tok], :] - zp) * scale
// V=128000, D=1024, G_SIZE=32, NG=32. Output fp32.
// R6: restore known-good R3 config (87.7 us): 4 tokens/block,
//     __builtin_nontemporal_store for output, cached weight loads.
//     R5's inline-asm "sc0 sc1 nt" store corrupted output — abandoned.

#define EMB_D   1024
#define EMB_NG  32
#define TOKS_PER_BLOCK 4

typedef float f32x4 __attribute__((ext_vector_type(4)));
typedef int   i32x4 __attribute__((ext_vector_type(4)));

__global__ __launch_bounds__(256) void int4_embed_dq_kernel(
    const int*   __restrict__ x,       // [ntok]
    const int*   __restrict__ weight,  // [V, D] int4 values stored as int32
    const float* __restrict__ scale,   // [V, NG]
    const int*   __restrict__ zp,      // [V, NG]
    float*       __restrict__ out,     // [ntok, D]
    int ntok)
{
    const int tok0 = blockIdx.x * TOKS_PER_BLOCK;
    const int t    = threadIdx.x;        // 0..255
    const int d0   = t << 2;             // 0,4,...,1020
    const int g    = d0 >> 5;            // group of 32

    if (tok0 + TOKS_PER_BLOCK <= ntok) {
        int v[TOKS_PER_BLOCK];
#pragma unroll
        for (int i = 0; i < TOKS_PER_BLOCK; ++i)
            v[i] = x[tok0 + i];

        i32x4 w4[TOKS_PER_BLOCK];
        float s [TOKS_PER_BLOCK];
        float z [TOKS_PER_BLOCK];
#pragma unroll
        for (int i = 0; i < TOKS_PER_BLOCK; ++i) {
            const size_t rowW = (size_t)v[i] * EMB_D;
            const size_t rowG = (size_t)v[i] * EMB_NG;
            w4[i] = *reinterpret_cast<const i32x4*>(&weight[rowW + d0]);
            s[i]  = scale[rowG + g];
            z[i]  = (float)zp[rowG + g];
        }
#pragma unroll
        for (int i = 0; i < TOKS_PER_BLOCK; ++i) {
            f32x4 o;
            o.x = ((float)w4[i].x - z[i]) * s[i];
            o.y = ((float)w4[i].y - z[i]) * s[i];
            o.z = ((float)w4[i].z - z[i]) * s[i];
            o.w = ((float)w4[i].w - z[i]) * s[i];
            __builtin_nontemporal_store(
                o, reinterpret_cast<f32x4*>(&out[(size_t)(tok0 + i) * EMB_D + d0]));
        }
    } else {
        for (int i = 0; i < TOKS_PER_BLOCK; ++i) {
            const int tok = tok0 + i;
            if (tok >= ntok) break;
            const int vv = x[tok];
            const size_t rowW = (size_t)vv * EMB_D;
            const size_t rowG = (size_t)vv * EMB_NG;
            const float ss = scale[rowG + g];
            const float zz = (float)zp[rowG + g];
            const i32x4 w4 = *reinterpret_cast<const i32x4*>(&weight[rowW + d0]);
            f32x4 o;
            o.x = ((float)w4.x - zz) * ss;
            o.y = ((float)w4.y - zz) * ss;
            o.z = ((float)w4.z - zz) * ss;
            o.w = ((float)w4.w - zz) * ss;
            __builtin_nontemporal_store(
                o, reinterpret_cast<f32x4*>(&out[(size_t)tok * EMB_D + d0]));
        }
    }
}

extern "C" void kernel_launch(void* const* d_in, const int* in_sizes, int n_in,
                              void* d_out, int out_size, void* d_ws, size_t ws_size,
                              hipStream_t stream) {
    const int*   x      = (const int*)d_in[0];
    const int*   weight = (const int*)d_in[1];
    const float* scale  = (const float*)d_in[2];
    const int*   zp     = (const int*)d_in[3];
    float*       out    = (float*)d_out;

    const int ntok = in_sizes[0];        // 32 * 2048 = 65536

    const int nblocks = (ntok + TOKS_PER_BLOCK - 1) / TOKS_PER_BLOCK;
    int4_embed_dq_kernel<<<dim3(nblocks), dim3(256), 0, stream>>>(
        x, weight, scale, zp, out, ntok);
}